// Round 3
// baseline (955.614 us; speedup 1.0000x reference)
//
#include <hip/hip_runtime.h>
#include <stdint.h>
#include <math.h>

#define WIDTH  1024
#define HEIGHT 1024
#define DDIM   128
#define TOPK   2048
#define CAP    131072     // > 1024*1024/9 strict 5x5 maxima bound
#define SELCAP 4096       // superset capacity: 2048 + boundary-bin (~200 expected)

// ---- workspace layout (bytes from d_ws) -----------------------------------
// hdr[0]=candidate count; hist[0..255]=coarse (key>>56), hist[256..65791]=fine (key>>48)
#define HIST_OFF 64
#define HIST_N   (256 + 65536)
#define KEYS_OFF (HIST_OFF + HIST_N * 4)          // 64 + 263168
#define SIDX_OFF (KEYS_OFF + CAP * 8)

// ---------------------------------------------------------------------------
// Kernel 1: 5x5 NMS via clamped reads (clipped window: duplicated border
// values don't change the max), 3x3 early exit. Per-row block: LDS candidate
// buffer -> ONE global atomic per block, then flush keys + two-level histogram.
// key = (score_bits<<32) | ~idx : monotone for score>0, ties -> ascending idx
// (== jax.lax.top_k tie rule).
// ---------------------------------------------------------------------------
__global__ __launch_bounds__(1024) void find_candidates(
        const float* __restrict__ feat,
        const int* __restrict__ p_ow, const int* __restrict__ p_oh,
        unsigned int* __restrict__ hdr,
        unsigned int* __restrict__ hist,
        unsigned long long* __restrict__ keys) {
    const int x = threadIdx.x;
    const int y = blockIdx.x;
    const float* hm = feat + (size_t)DDIM * WIDTH * HEIGHT;

    __shared__ unsigned long long lkeys[256];
    __shared__ unsigned int lcnt, lbase;
    if (x == 0) lcnt = 0u;
    __syncthreads();

    float c = hm[y * WIDTH + x];
    // heatmap > 0 (rejects NaN too) & in_bounds
    if ((c > 0.0f) && (x <= p_ow[0] - 1) && (y <= p_oh[0] - 1)) {
        int xm2 = max(x - 2, 0), xm1 = max(x - 1, 0);
        int xp1 = min(x + 1, WIDTH - 1), xp2 = min(x + 2, WIDTH - 1);
        int ym2 = max(y - 2, 0), ym1 = max(y - 1, 0);
        int yp1 = min(y + 1, HEIGHT - 1), yp2 = min(y + 2, HEIGHT - 1);
        const float* r0 = hm + ym1 * WIDTH;
        const float* r1 = hm + y   * WIDTH;
        const float* r2 = hm + yp1 * WIDTH;
        // inner 3x3 ring first (8 loads) — rejects ~8/9 of positives
        float m = fmaxf(fmaxf(fmaxf(r0[xm1], r0[x]), fmaxf(r0[xp1], r1[xm1])),
                        fmaxf(fmaxf(r1[xp1], r2[xm1]), fmaxf(r2[x], r2[xp1])));
        if (m <= c) {
            const float* ra = hm + ym2 * WIDTH;
            const float* rb = hm + yp2 * WIDTH;
            float m2 = fmaxf(fmaxf(fmaxf(ra[xm2], ra[xm1]), fmaxf(ra[x], ra[xp1])), ra[xp2]);
            m2 = fmaxf(m2, fmaxf(fmaxf(rb[xm2], rb[xm1]), fmaxf(fmaxf(rb[x], rb[xp1]), rb[xp2])));
            m2 = fmaxf(m2, fmaxf(fmaxf(r0[xm2], r0[xp2]), fmaxf(r1[xm2], r1[xp2])));
            m2 = fmaxf(m2, fmaxf(r2[xm2], r2[xp2]));
            if (m2 <= c) {   // strict local max of clipped 5x5 window
                unsigned int idx = (unsigned int)(y * WIDTH + x);
                unsigned long long key =
                    ((unsigned long long)__float_as_uint(c) << 32) |
                    (unsigned long long)(~idx);
                unsigned int p = atomicAdd(&lcnt, 1u);
                if (p < 256u) lkeys[p] = key;
            }
        }
    }
    __syncthreads();
    if (x == 0) lbase = atomicAdd(&hdr[0], lcnt);
    __syncthreads();
    unsigned int n = lcnt < 256u ? lcnt : 256u;
    unsigned int base = lbase;
    for (unsigned int i = x; i < n; i += blockDim.x) {
        unsigned long long k = lkeys[i];
        if (base + i < CAP) keys[base + i] = k;
        atomicAdd(&hist[(unsigned int)(k >> 56)], 1u);          // coarse
        atomicAdd(&hist[256u + (unsigned int)(k >> 48)], 1u);   // fine
    }
}

// ---------------------------------------------------------------------------
// Kernel 2 (fused): one block.
//  (a) two-level threshold: suffix-scan 256 coarse bins -> coarse bin Bc, then
//      256 fine bins inside Bc -> 16-bit threshold B. 2 KB of histogram reads.
//  (b) filter the key stream: (k>>48) >= B -> LDS (wave-ballot aggregated
//      append). Selected set is a superset of the exact top-K (~2.3K keys).
//  (c) bitonic sort SELCAP (0-padded) descending; emit exact top-TOPK.
// Keys are unique 64-bit (score_bits | ~idx), so sorted prefix == lax.top_k
// order including the ascending-index tie rule.
// ---------------------------------------------------------------------------
__global__ __launch_bounds__(1024) void select_sort_emit(
        const unsigned int* __restrict__ hdr,
        const unsigned int* __restrict__ hist,
        const unsigned long long* __restrict__ keys,
        float* __restrict__ out_kp, float* __restrict__ out_sc,
        float* __restrict__ out_vd, unsigned int* __restrict__ sidx) {
    __shared__ unsigned long long sk[SELCAP];
    __shared__ unsigned int scn[256];
    __shared__ unsigned int sBc, sAc, sB, sCnt;
    const int tid = threadIdx.x;
    const int lane = tid & 63;

    unsigned int N = hdr[0]; if (N > CAP) N = CAP;
    unsigned int target = N < TOPK ? N : TOPK;   // == KK

    if (tid == 0) { sBc = 0u; sAc = 0u; sB = 0u; sCnt = 0u; }
    // ---- coarse suffix scan (bins = key>>56) ----
    if (tid < 256) scn[tid] = hist[tid];
    __syncthreads();
    for (int d = 1; d < 256; d <<= 1) {
        unsigned int v = 0u;
        if (tid < 256 && tid + d < 256) v = scn[tid + d];
        __syncthreads();
        if (tid < 256) scn[tid] += v;
        __syncthreads();
    }
    if (tid < 256 && target > 0) {
        unsigned int St = scn[tid];
        unsigned int Sn = (tid < 255) ? scn[tid + 1] : 0u;
        if (St >= target && Sn < target) { sBc = (unsigned int)tid; sAc = Sn; }
    }
    __syncthreads();
    // ---- fine suffix scan within coarse bin Bc ----
    unsigned int bc = sBc, ac = sAc;
    if (tid < 256) scn[tid] = hist[256u + bc * 256u + (unsigned int)tid];
    __syncthreads();
    for (int d = 1; d < 256; d <<= 1) {
        unsigned int v = 0u;
        if (tid < 256 && tid + d < 256) v = scn[tid + d];
        __syncthreads();
        if (tid < 256) scn[tid] += v;
        __syncthreads();
    }
    if (tid < 256 && target > 0) {
        unsigned int St = ac + scn[tid];
        unsigned int Sn = ac + ((tid < 255) ? scn[tid + 1] : 0u);
        if (St >= target && Sn < target) sB = (bc << 8) | (unsigned int)tid;
    }
    __syncthreads();
    unsigned int B = sB;

    // ---- filter keys -> LDS (per-wave ballot-aggregated append) ----
    if (target > 0) {
        for (unsigned int i = tid; i < ((N + 1023u) & ~1023u); i += 1024u) {
            unsigned long long k = (i < N) ? keys[i] : 0ull;
            bool pred = (i < N) && ((unsigned int)(k >> 48) >= B);
            unsigned long long mask = __ballot(pred);
            if (mask) {
                int leader = (int)(__ffsll((long long)mask) - 1);
                unsigned int wbase = 0u;
                if (lane == leader) wbase = atomicAdd(&sCnt, (unsigned int)__popcll(mask));
                wbase = (unsigned int)__shfl((int)wbase, leader, 64);
                if (pred) {
                    unsigned int p = wbase + (unsigned int)__popcll(mask & ((1ull << lane) - 1ull));
                    if (p < SELCAP) sk[p] = k;
                }
            }
        }
    }
    __syncthreads();
    unsigned int M = sCnt < SELCAP ? sCnt : SELCAP;
    for (unsigned int i = M + tid; i < SELCAP; i += 1024u) sk[i] = 0ull;
    __syncthreads();

    // ---- bitonic sort, descending, SELCAP elems ----
    for (unsigned int size = 2; size <= SELCAP; size <<= 1) {
        for (unsigned int str = size >> 1; str > 0; str >>= 1) {
            for (unsigned int i = tid; i < SELCAP; i += 1024u) {
                unsigned int j = i ^ str;
                if (j > i) {
                    unsigned long long a = sk[i], b = sk[j];
                    bool desc = ((i & size) == 0);
                    if (desc ? (a < b) : (a > b)) { sk[i] = b; sk[j] = a; }
                }
            }
            __syncthreads();
        }
    }

    // ---- emit ----
    for (unsigned int r = tid; r < TOPK; r += 1024u) {
        unsigned long long k = sk[r];
        bool live = (r < target);
        unsigned int idx = ~(unsigned int)(k & 0xFFFFFFFFull);
        out_kp[2 * r + 0] = live ? (float)(idx & (WIDTH - 1)) : 0.0f;
        out_kp[2 * r + 1] = live ? (float)(idx >> 10) : 0.0f;
        out_sc[r] = live ? __uint_as_float((unsigned int)(k >> 32)) : -INFINITY;
        out_vd[r] = live ? 1.0f : 0.0f;
        sidx[r]   = live ? idx : 0u;
    }
}

// ---------------------------------------------------------------------------
// Kernel 3: descriptor gather + L2 normalize. One block/keypoint, 128 ch.
// Channel-major layout -> loads are inherently scattered (128 lines/kp,
// 16.8 MB total fetch ~ 2.7 us at HBM rate).
// ---------------------------------------------------------------------------
__global__ __launch_bounds__(128) void gather_desc(
        const float* __restrict__ feat,
        const unsigned int* __restrict__ sidx,
        float* __restrict__ out_d) {
    int kp = blockIdx.x;
    int c  = threadIdx.x;
    unsigned int idx = sidx[kp];
    float v = feat[(size_t)c * (WIDTH * HEIGHT) + idx];
    float s = v * v;
    #pragma unroll
    for (int off = 32; off > 0; off >>= 1) s += __shfl_down(s, off, 64);
    __shared__ float sw[2];
    if ((c & 63) == 0) sw[c >> 6] = s;
    __syncthreads();
    float norm = fmaxf(sqrtf(sw[0] + sw[1]), 1e-12f);
    out_d[(size_t)kp * DDIM + c] = v / norm;
}

// ---------------------------------------------------------------------------
extern "C" void kernel_launch(void* const* d_in, const int* in_sizes, int n_in,
                              void* d_out, int out_size, void* d_ws, size_t ws_size,
                              hipStream_t stream) {
    const float* feat = (const float*)d_in[0];
    const int* p_ow = (const int*)d_in[1];
    const int* p_oh = (const int*)d_in[2];
    // d_in[3]=max_keypoints(2048), d_in[4]=window(5): baked into TOPK / radius 2.

    float* out = (float*)d_out;
    float* out_kp = out;                              // 2048*2
    float* out_sc = out + 2 * TOPK;                   // 2048
    float* out_d  = out + 3 * TOPK;                   // 2048*128
    float* out_vd = out + 3 * TOPK + TOPK * DDIM;     // 2048

    unsigned int* hdr  = (unsigned int*)d_ws;
    unsigned int* hist = (unsigned int*)((char*)d_ws + HIST_OFF);
    unsigned long long* keys = (unsigned long long*)((char*)d_ws + KEYS_OFF);
    unsigned int* sidx = (unsigned int*)((char*)d_ws + SIDX_OFF);

    hipMemsetAsync(d_ws, 0, KEYS_OFF, stream);        // hdr + 257 KiB histograms

    find_candidates<<<HEIGHT, 1024, 0, stream>>>(feat, p_ow, p_oh, hdr, hist, keys);
    select_sort_emit<<<1, 1024, 0, stream>>>(hdr, hist, keys,
                                             out_kp, out_sc, out_vd, sidx);
    gather_desc<<<TOPK, DDIM, 0, stream>>>(feat, sidx, out_d);
}

// Round 4
// 953.283 us; speedup vs baseline: 1.0024x; 1.0024x over previous
//
#include <hip/hip_runtime.h>
#include <stdint.h>
#include <math.h>

#define WIDTH  1024
#define HEIGHT 1024
#define DDIM   128
#define TOPK   2048
#define CAP    131072     // > 1024*1024/9 strict 5x5 maxima bound
#define SELCAP 4096       // superset capacity: 2048 + boundary-bin (~200 expected)
#define ROWCAP 512        // per-row candidate cap (spacing>=3 bound is 342)

// ---- workspace layout (bytes from d_ws) -----------------------------------
// hdr[0]=candidate count; hist[0..255]=coarse (key>>56), hist[256..65791]=fine (key>>48)
#define HIST_OFF 64
#define HIST_N   (256 + 65536)
#define KEYS_OFF (HIST_OFF + HIST_N * 4)
#define SIDX_OFF (KEYS_OFF + CAP * 8)

// ---------------------------------------------------------------------------
// Kernel 1: 5x5 NMS, one block per row. The 5 clamped rows are staged in LDS
// via coalesced float4 loads; 256 threads x 4 strided pixels (x = t + 256*px)
// so LDS window reads are stride-1 across lanes (conflict-free). 3x3 early
// exit rejects ~8/9 of positives. Per-block LDS candidate buffer -> ONE global
// atomic, then flush keys + two-level histogram.
// key = (score_bits<<32) | ~idx : monotone for score>0, ties -> ascending idx
// (== jax.lax.top_k tie rule).
// ---------------------------------------------------------------------------
__global__ __launch_bounds__(256) void find_candidates(
        const float* __restrict__ feat,
        const int* __restrict__ p_ow, const int* __restrict__ p_oh,
        unsigned int* __restrict__ hdr,
        unsigned int* __restrict__ hist,
        unsigned long long* __restrict__ keys) {
    const int t = threadIdx.x;
    const int y = blockIdx.x;
    const float* hm = feat + (size_t)DDIM * WIDTH * HEIGHT;

    __shared__ __align__(16) float srow[5][WIDTH];
    __shared__ unsigned long long lkeys[ROWCAP];
    __shared__ unsigned int lcnt, lbase;
    if (t == 0) lcnt = 0u;

    #pragma unroll
    for (int r = 0; r < 5; ++r) {
        int yy = y - 2 + r;
        yy = yy < 0 ? 0 : (yy > HEIGHT - 1 ? HEIGHT - 1 : yy);
        const float4* src = (const float4*)(hm + (size_t)yy * WIDTH);
        ((float4*)&srow[r][0])[t] = src[t];
    }
    __syncthreads();

    const int ow = p_ow[0], oh = p_oh[0];
    const bool yok = (y <= oh - 1);
    #pragma unroll
    for (int px = 0; px < 4; ++px) {
        int x = t + 256 * px;
        float c = srow[2][x];
        // heatmap > 0 (rejects NaN too) & in_bounds
        if ((c > 0.0f) && yok && (x <= ow - 1)) {
            int xm1 = max(x - 1, 0), xp1 = min(x + 1, WIDTH - 1);
            // inner 3x3 ring (8 LDS reads) — rejects ~8/9 of positives
            float m = fmaxf(fmaxf(fmaxf(srow[1][xm1], srow[1][x]),
                                  fmaxf(srow[1][xp1], srow[2][xm1])),
                            fmaxf(fmaxf(srow[2][xp1], srow[3][xm1]),
                                  fmaxf(srow[3][x],   srow[3][xp1])));
            if (m <= c) {
                int xm2 = max(x - 2, 0), xp2 = min(x + 2, WIDTH - 1);
                float m2 = fmaxf(fmaxf(fmaxf(srow[0][xm2], srow[0][xm1]),
                                       fmaxf(srow[0][x],   srow[0][xp1])), srow[0][xp2]);
                m2 = fmaxf(m2, fmaxf(fmaxf(srow[4][xm2], srow[4][xm1]),
                                     fmaxf(fmaxf(srow[4][x], srow[4][xp1]), srow[4][xp2])));
                m2 = fmaxf(m2, fmaxf(fmaxf(srow[1][xm2], srow[1][xp2]),
                                     fmaxf(srow[2][xm2], srow[2][xp2])));
                m2 = fmaxf(m2, fmaxf(srow[3][xm2], srow[3][xp2]));
                if (m2 <= c) {   // strict local max of clipped 5x5 window
                    unsigned int idx = (unsigned int)(y * WIDTH + x);
                    unsigned long long key =
                        ((unsigned long long)__float_as_uint(c) << 32) |
                        (unsigned long long)(~idx);
                    unsigned int p = atomicAdd(&lcnt, 1u);
                    if (p < ROWCAP) lkeys[p] = key;
                }
            }
        }
    }
    __syncthreads();
    if (t == 0) lbase = atomicAdd(&hdr[0], lcnt);
    __syncthreads();
    unsigned int n = lcnt < ROWCAP ? lcnt : ROWCAP;
    unsigned int base = lbase;
    for (unsigned int i = t; i < n; i += blockDim.x) {
        unsigned long long k = lkeys[i];
        if (base + i < CAP) keys[base + i] = k;
        atomicAdd(&hist[(unsigned int)(k >> 56)], 1u);          // coarse
        atomicAdd(&hist[256u + (unsigned int)(k >> 48)], 1u);   // fine
    }
}

// ---------------------------------------------------------------------------
// Kernel 2 (fused): one block.
//  (a) two-level threshold: suffix-scan 256 coarse bins -> coarse bin Bc, then
//      256 fine bins inside Bc -> 16-bit threshold B. 2 KB of histogram reads.
//  (b) filter the key stream: (k>>48) >= B -> LDS (wave-ballot aggregated
//      append). Selected set is a superset of the exact top-K (~2.3K keys).
//  (c) bitonic sort SELCAP (0-padded) descending; emit exact top-TOPK.
// Keys are unique 64-bit (score_bits | ~idx), so sorted prefix == lax.top_k
// order including the ascending-index tie rule.
// ---------------------------------------------------------------------------
__global__ __launch_bounds__(1024) void select_sort_emit(
        const unsigned int* __restrict__ hdr,
        const unsigned int* __restrict__ hist,
        const unsigned long long* __restrict__ keys,
        float* __restrict__ out_kp, float* __restrict__ out_sc,
        float* __restrict__ out_vd, unsigned int* __restrict__ sidx) {
    __shared__ unsigned long long sk[SELCAP];
    __shared__ unsigned int scn[256];
    __shared__ unsigned int sBc, sAc, sB, sCnt;
    const int tid = threadIdx.x;
    const int lane = tid & 63;

    unsigned int N = hdr[0]; if (N > CAP) N = CAP;
    unsigned int target = N < TOPK ? N : TOPK;   // == KK

    if (tid == 0) { sBc = 0u; sAc = 0u; sB = 0u; sCnt = 0u; }
    // ---- coarse suffix scan (bins = key>>56) ----
    if (tid < 256) scn[tid] = hist[tid];
    __syncthreads();
    for (int d = 1; d < 256; d <<= 1) {
        unsigned int v = 0u;
        if (tid < 256 && tid + d < 256) v = scn[tid + d];
        __syncthreads();
        if (tid < 256) scn[tid] += v;
        __syncthreads();
    }
    if (tid < 256 && target > 0) {
        unsigned int St = scn[tid];
        unsigned int Sn = (tid < 255) ? scn[tid + 1] : 0u;
        if (St >= target && Sn < target) { sBc = (unsigned int)tid; sAc = Sn; }
    }
    __syncthreads();
    // ---- fine suffix scan within coarse bin Bc ----
    unsigned int bc = sBc, ac = sAc;
    if (tid < 256) scn[tid] = hist[256u + bc * 256u + (unsigned int)tid];
    __syncthreads();
    for (int d = 1; d < 256; d <<= 1) {
        unsigned int v = 0u;
        if (tid < 256 && tid + d < 256) v = scn[tid + d];
        __syncthreads();
        if (tid < 256) scn[tid] += v;
        __syncthreads();
    }
    if (tid < 256 && target > 0) {
        unsigned int St = ac + scn[tid];
        unsigned int Sn = ac + ((tid < 255) ? scn[tid + 1] : 0u);
        if (St >= target && Sn < target) sB = (bc << 8) | (unsigned int)tid;
    }
    __syncthreads();
    unsigned int B = sB;

    // ---- filter keys -> LDS (per-wave ballot-aggregated append) ----
    if (target > 0) {
        for (unsigned int i = tid; i < ((N + 1023u) & ~1023u); i += 1024u) {
            unsigned long long k = (i < N) ? keys[i] : 0ull;
            bool pred = (i < N) && ((unsigned int)(k >> 48) >= B);
            unsigned long long mask = __ballot(pred);
            if (mask) {
                int leader = (int)(__ffsll((long long)mask) - 1);
                unsigned int wbase = 0u;
                if (lane == leader) wbase = atomicAdd(&sCnt, (unsigned int)__popcll(mask));
                wbase = (unsigned int)__shfl((int)wbase, leader, 64);
                if (pred) {
                    unsigned int p = wbase + (unsigned int)__popcll(mask & ((1ull << lane) - 1ull));
                    if (p < SELCAP) sk[p] = k;
                }
            }
        }
    }
    __syncthreads();
    unsigned int M = sCnt < SELCAP ? sCnt : SELCAP;
    for (unsigned int i = M + tid; i < SELCAP; i += 1024u) sk[i] = 0ull;
    __syncthreads();

    // ---- bitonic sort, descending, SELCAP elems ----
    for (unsigned int size = 2; size <= SELCAP; size <<= 1) {
        for (unsigned int str = size >> 1; str > 0; str >>= 1) {
            for (unsigned int i = tid; i < SELCAP; i += 1024u) {
                unsigned int j = i ^ str;
                if (j > i) {
                    unsigned long long a = sk[i], b = sk[j];
                    bool desc = ((i & size) == 0);
                    if (desc ? (a < b) : (a > b)) { sk[i] = b; sk[j] = a; }
                }
            }
            __syncthreads();
        }
    }

    // ---- emit ----
    for (unsigned int r = tid; r < TOPK; r += 1024u) {
        unsigned long long k = sk[r];
        bool live = (r < target);
        unsigned int idx = ~(unsigned int)(k & 0xFFFFFFFFull);
        out_kp[2 * r + 0] = live ? (float)(idx & (WIDTH - 1)) : 0.0f;
        out_kp[2 * r + 1] = live ? (float)(idx >> 10) : 0.0f;
        out_sc[r] = live ? __uint_as_float((unsigned int)(k >> 32)) : -INFINITY;
        out_vd[r] = live ? 1.0f : 0.0f;
        sidx[r]   = live ? idx : 0u;
    }
}

// ---------------------------------------------------------------------------
// Kernel 3: descriptor gather + L2 normalize. One block/keypoint, 128 ch.
// Channel-major layout -> loads are inherently scattered (128 lines/kp,
// ~16.8 MB line-granular fetch ~ 3 us at HBM rate, latency-hidden by
// 2048 blocks across 256 CUs).
// ---------------------------------------------------------------------------
__global__ __launch_bounds__(128) void gather_desc(
        const float* __restrict__ feat,
        const unsigned int* __restrict__ sidx,
        float* __restrict__ out_d) {
    int kp = blockIdx.x;
    int c  = threadIdx.x;
    unsigned int idx = sidx[kp];
    float v = feat[(size_t)c * (WIDTH * HEIGHT) + idx];
    float s = v * v;
    #pragma unroll
    for (int off = 32; off > 0; off >>= 1) s += __shfl_down(s, off, 64);
    __shared__ float sw[2];
    if ((c & 63) == 0) sw[c >> 6] = s;
    __syncthreads();
    float norm = fmaxf(sqrtf(sw[0] + sw[1]), 1e-12f);
    out_d[(size_t)kp * DDIM + c] = v / norm;
}

// ---------------------------------------------------------------------------
extern "C" void kernel_launch(void* const* d_in, const int* in_sizes, int n_in,
                              void* d_out, int out_size, void* d_ws, size_t ws_size,
                              hipStream_t stream) {
    const float* feat = (const float*)d_in[0];
    const int* p_ow = (const int*)d_in[1];
    const int* p_oh = (const int*)d_in[2];
    // d_in[3]=max_keypoints(2048), d_in[4]=window(5): baked into TOPK / radius 2.

    float* out = (float*)d_out;
    float* out_kp = out;                              // 2048*2
    float* out_sc = out + 2 * TOPK;                   // 2048
    float* out_d  = out + 3 * TOPK;                   // 2048*128
    float* out_vd = out + 3 * TOPK + TOPK * DDIM;     // 2048

    unsigned int* hdr  = (unsigned int*)d_ws;
    unsigned int* hist = (unsigned int*)((char*)d_ws + HIST_OFF);
    unsigned long long* keys = (unsigned long long*)((char*)d_ws + KEYS_OFF);
    unsigned int* sidx = (unsigned int*)((char*)d_ws + SIDX_OFF);

    hipMemsetAsync(d_ws, 0, KEYS_OFF, stream);        // hdr + 257 KiB histograms

    find_candidates<<<HEIGHT, 256, 0, stream>>>(feat, p_ow, p_oh, hdr, hist, keys);
    select_sort_emit<<<1, 1024, 0, stream>>>(hdr, hist, keys,
                                             out_kp, out_sc, out_vd, sidx);
    gather_desc<<<TOPK, DDIM, 0, stream>>>(feat, sidx, out_d);
}